// Round 13
// baseline (27119.757 us; speedup 1.0000x reference)
//
#include <hip/hip_runtime.h>

#define NWG 256
#define NT  512
#define NDIM 4096
#define MROWS 2048
#define N_ADMM 30
#define N_CG 15

typedef unsigned long long ull;
typedef float f32x4 __attribute__((ext_vector_type(4)));

// 16B-chunk XOR swizzle: breaks the stride-128B -> same-bank pattern of the
// G-mult ds_read_b128s (bank = chunk%8; xor with chunk>>3 spreads 8 ways).
#define SWZC(c) ((c) ^ (((c) >> 3) & 7))

__device__ __forceinline__ float wred64(float v) {
#pragma unroll
  for (int m = 32; m > 0; m >>= 1) v += __shfl_xor(v, m, 64);
  return v;
}
__device__ __forceinline__ void sta32(unsigned* p, unsigned v) {
  __hip_atomic_store(p, v, __ATOMIC_RELAXED, __HIP_MEMORY_SCOPE_AGENT);
}
__device__ __forceinline__ unsigned lda32(const unsigned* p) {
  return __hip_atomic_load(p, __ATOMIC_RELAXED, __HIP_MEMORY_SCOPE_AGENT);
}
__device__ __forceinline__ void staf(float* p, float v) {
  __hip_atomic_store((unsigned*)p, __float_as_uint(v), __ATOMIC_RELAXED,
                     __HIP_MEMORY_SCOPE_AGENT);
}
__device__ __forceinline__ f32x4 ntf4(const float* p) {
  return __builtin_nontemporal_load((const f32x4*)p);
}
__device__ __forceinline__ float ntf(const float* p) {
  return __builtin_nontemporal_load(p);
}

// -------- workspace layout --------------------------------------------------
#define WS_KILL 128
#define WS_FLAG 8192     // 256 slots x 64B, uint gen (payload-free, monotone)
#define WS_NB0  49152    // n-space exchange bank0: 4096 f32 (Kp / r0 / Gdiag)
#define WS_NB1  65536    // bank1 (gen-parity ping-pong)
#define WS_U    81920    // m-space u: 2048 f32 (single buffer; WAR-safe by gates)

__global__ __launch_bounds__(NT, 2)
void admm_lp_kernel(const float* __restrict__ A, const float* __restrict__ cvec,
                    const float* __restrict__ lbv, const float* __restrict__ ubv,
                    const float* __restrict__ dvec, const float* __restrict__ evec,
                    const float* __restrict__ gcp, const float* __restrict__ gbp,
                    const float* __restrict__ rhop, const float* __restrict__ sigp,
                    const float* __restrict__ alp,
                    float* __restrict__ out, unsigned char* __restrict__ ws)
{
  const int tid = threadIdx.x;
  const int w = blockIdx.x;
  const int wv = tid >> 6, lane = tid & 63;
  const int j0 = tid * 8;          // this thread's 8-element n-space slice
  const int q  = tid >> 7;         // G row-quad 0..3 (rows w*16+q*4 .. +3)
  const int kt = tid & 127;        // G k-thread (cols kt*32 .. +31)
  const int gg = tid >> 4, gl = tid & 15;   // B-phase col-slice mapping

  unsigned* kill  = (unsigned*)(ws + WS_KILL);
  unsigned* flags = (unsigned*)(ws + WS_FLAG);
  float* nbuf[2] = { (float*)(ws + WS_NB0), (float*)(ws + WS_NB1) };
  float* u_g = (float*)(ws + WS_U);

  __shared__ float s_scal[8];
  __shared__ float dredA[8], dredB[8];
  __shared__ float dred8[8][8];
  __shared__ float sredA[32][16];
  __shared__ float pmat[16][132];            // padded: 16-thread reduce 2-way banks
  __shared__ float cs_lds[16], xchunk[16], diag16[16];
  __shared__ float mzb[8], myb[8], mlb[8], mub[8];
  __shared__ int s_dead;
  __shared__ float ldsA[4096];   // swizzled: p/xt stage (CG); GEMM buf A
  __shared__ float ldsB[4096];   // GEMM buf B; B-phase u_lds (first 2048, linear)

  float Greg[4][32];             // G[w*16+q*4+rr][kt*32+cc]  (128 VGPR)
  float p8[8], r8[8], xt8[8], x8[8], Md8[8];
  unsigned gen = 0;

  // one-hop producer wait: wave v's data comes from producers v*32..v*32+31
  // (holds for Kp/r0/diag n-slices AND the B-phase u rows). Flags are
  // payload-free monotone gens -> single bank, overwrite-with-larger is safe.
  auto wait_prod = [&](unsigned G) {
    if (s_dead) return;
    unsigned* fp = &flags[(size_t)(wv * 32 + (lane & 31)) * 16];
    int spin = 0;
    for (;;) {
      unsigned v = lda32(fp);
      if (__all(v >= G)) break;
      __builtin_amdgcn_s_sleep(1);
      if ((++spin & 127) == 0) {
        if (lda32(kill) != 0u || spin > 2000000) {
          s_dead = 1; sta32(kill, 1u); break;
        }
      }
    }
    asm volatile("" ::: "memory");
    __builtin_amdgcn_sched_barrier(0);
  };

  // all exchange-data stores are wave0 (tid<16 / tid<8) -> wave0's vmcnt(0)
  // drains them before the flag store. ++gen uniform across all threads.
  auto publish = [&]() {
    if (wv == 0) {
      asm volatile("s_waitcnt vmcnt(0)" ::: "memory");
      __builtin_amdgcn_sched_barrier(0);
      if (lane == 0 && !s_dead) sta32(&flags[(size_t)w * 16], gen + 1);
    }
    ++gen;
  };

  // ---------------- prologue: scalars, m-state, G = A^T A (own 16 rows) -------
  if (tid == 0) {
    s_scal[0] = sigp[0]; s_scal[1] = rhop[0]; s_scal[2] = alp[0];
    s_scal[3] = gcp[0];  s_scal[4] = gbp[0];
    s_dead = 0;
  }
  __syncthreads();
  const float sig = s_scal[0], rho = s_scal[1], al = s_scal[2];
  const float gc = s_scal[3], gb = s_scal[4];

  if (tid < 8) {
    const int rm = w * 8 + tid;
    mzb[tid] = 0.f; myb[tid] = 0.f;
    const float ee = evec[rm];
    mlb[tid] = gb * ee * lbv[rm];
    mub[tid] = gb * ee * ubv[rm];
  }
  if (tid < 16) {
    const int j = w * 16 + tid;
    cs_lds[tid] = gc * dvec[j] * cvec[j];
  }

#pragma unroll
  for (int rr = 0; rr < 4; ++rr)
#pragma unroll
    for (int cc = 0; cc < 32; ++cc) Greg[rr][cc] = 0.f;

  // software-pipelined row stream: LDS double-buffer + register prefetch
  {
    f32x4 pf0 = ntf4(A + j0), pf1 = ntf4(A + j0 + 4);        // row 0
    *(f32x4*)&ldsA[SWZC(2 * tid) * 4]     = pf0;
    *(f32x4*)&ldsA[SWZC(2 * tid + 1) * 4] = pf1;
    pf0 = ntf4(A + NDIM + j0); pf1 = ntf4(A + NDIM + j0 + 4); // row 1
    __syncthreads();
    float* bc = ldsA;
    float* bn = ldsB;
#pragma unroll 1
    for (int i = 0; i < MROWS; ++i) {
      if (i + 1 < MROWS) {
        *(f32x4*)&bn[SWZC(2 * tid) * 4]     = pf0;
        *(f32x4*)&bn[SWZC(2 * tid + 1) * 4] = pf1;
      }
      if (i + 2 < MROWS) {
        pf0 = ntf4(A + (size_t)(i + 2) * NDIM + j0);
        pf1 = ntf4(A + (size_t)(i + 2) * NDIM + j0 + 4);
      }
      const f32x4 av = *(f32x4*)&bc[SWZC(w * 4 + q) * 4];   // A[i, own 4 rows]
#pragma unroll
      for (int c4 = 0; c4 < 8; ++c4) {
        const f32x4 kv = *(f32x4*)&bc[SWZC(kt * 8 + c4) * 4];
#pragma unroll
        for (int e = 0; e < 4; ++e) {
          const float kvv = kv[e];
          const int cc = c4 * 4 + e;
          Greg[0][cc] += av.x * kvv;
          Greg[1][cc] += av.y * kvv;
          Greg[2][cc] += av.z * kvv;
          Greg[3][cc] += av.w * kvv;
        }
      }
      __syncthreads();
      float* t = bc; bc = bn; bn = t;
    }
  }

  // G diagonal -> Md (one exchange): row j=w*16+q*4+rr sits at kt=w>>1,
  // cc=(w&1)*16+q*4+rr
  if (kt == (w >> 1)) {
#pragma unroll
    for (int rr = 0; rr < 4; ++rr)
      diag16[q * 4 + rr] = Greg[rr][(w & 1) * 16 + q * 4 + rr];
  }
  __syncthreads();
  if (tid < 16) staf(&nbuf[1][w * 16 + tid], diag16[tid]);
  publish();                       // gen 1
  wait_prod(gen);
  {
    const f32x4 d0 = ntf4(&nbuf[1][j0]), d1 = ntf4(&nbuf[1][j0 + 4]);
#pragma unroll
    for (int e = 0; e < 4; ++e) { Md8[e] = sig + rho * d0[e]; Md8[4 + e] = sig + rho * d1[e]; }
  }
#pragma unroll
  for (int e = 0; e < 8; ++e) { xt8[e] = 0.f; x8[e] = 0.f; }

  float rz = 1.f;

  // ---------------- main loop --------------------------------------------------
#pragma unroll 1
  for (int admm = 0; admm < N_ADMM; ++admm) {
#pragma unroll 1
    for (int cg = 0; cg <= N_CG; ++cg) {
      if (cg == 0) {
        // ---- acquire r0; z=r/Md; rz; p=z -------------------------------------
        if (admm == 0) {
          const f32x4 dv0 = ntf4(dvec + j0), dv1 = ntf4(dvec + j0 + 4);
          const f32x4 cv0 = ntf4(cvec + j0), cv1 = ntf4(cvec + j0 + 4);
#pragma unroll
          for (int e = 0; e < 4; ++e) {
            r8[e]     = -gc * dv0[e] * cv0[e];
            r8[4 + e] = -gc * dv1[e] * cv1[e];
          }
        } else {
          wait_prod(gen);
          const f32x4 a = ntf4(&nbuf[gen & 1][j0]), b = ntf4(&nbuf[gen & 1][j0 + 4]);
#pragma unroll
          for (int e = 0; e < 4; ++e) { r8[e] = a[e]; r8[4 + e] = b[e]; }
        }
        float z8[8], part = 0.f;
#pragma unroll
        for (int e = 0; e < 8; ++e) { z8[e] = r8[e] / Md8[e]; part += r8[e] * z8[e]; }
        part = wred64(part);
        if (lane == 0) dredA[wv] = part;
        __syncthreads();
        rz = dredA[0] + dredA[1] + dredA[2] + dredA[3]
           + dredA[4] + dredA[5] + dredA[6] + dredA[7];
#pragma unroll
        for (int e = 0; e < 8; ++e) p8[e] = z8[e];
      } else {
        // ---- acquire Kp; alpha; xt; (r,z,rz,beta,p unless last) --------------
        wait_prod(gen);
        const f32x4 a = ntf4(&nbuf[gen & 1][j0]), b = ntf4(&nbuf[gen & 1][j0 + 4]);
        float Kp8[8];
#pragma unroll
        for (int e = 0; e < 4; ++e) { Kp8[e] = a[e]; Kp8[4 + e] = b[e]; }
        float part = 0.f;
#pragma unroll
        for (int e = 0; e < 8; ++e) part += p8[e] * Kp8[e];
        part = wred64(part);
        if (lane == 0) dredA[wv] = part;
        __syncthreads();
        const float pKp = dredA[0] + dredA[1] + dredA[2] + dredA[3]
                        + dredA[4] + dredA[5] + dredA[6] + dredA[7];
        const float alpha = rz / pKp;
#pragma unroll
        for (int e = 0; e < 8; ++e) xt8[e] += alpha * p8[e];
        if (cg < N_CG) {
          float z8[8], pb = 0.f;
#pragma unroll
          for (int e = 0; e < 8; ++e) {
            r8[e] -= alpha * Kp8[e];
            z8[e] = r8[e] / Md8[e];
            pb += r8[e] * z8[e];
          }
          pb = wred64(pb);
          if (lane == 0) dredB[wv] = pb;
          __syncthreads();
          const float rzn = dredB[0] + dredB[1] + dredB[2] + dredB[3]
                          + dredB[4] + dredB[5] + dredB[6] + dredB[7];
          const float beta = rzn / rz;
          rz = rzn;
#pragma unroll
          for (int e = 0; e < 8; ++e) p8[e] = z8[e] + beta * p8[e];
        }
      }
      if (cg < N_CG) {
        // ---- Kp_next = rho*(G p) + sig*p on own 16; publish 64 B -------------
        {
          f32x4 v0, v1;
#pragma unroll
          for (int e = 0; e < 4; ++e) { v0[e] = p8[e]; v1[e] = p8[4 + e]; }
          *(f32x4*)&ldsA[SWZC(2 * tid) * 4]     = v0;
          *(f32x4*)&ldsA[SWZC(2 * tid + 1) * 4] = v1;
        }
        __syncthreads();
        float u0 = 0.f, u1 = 0.f, u2 = 0.f, u3 = 0.f;
#pragma unroll
        for (int c4 = 0; c4 < 8; ++c4) {
          const f32x4 kv = *(f32x4*)&ldsA[SWZC(kt * 8 + c4) * 4];
#pragma unroll
          for (int e = 0; e < 4; ++e) {
            const float pv = kv[e];
            const int cc = c4 * 4 + e;
            u0 += Greg[0][cc] * pv; u1 += Greg[1][cc] * pv;
            u2 += Greg[2][cc] * pv; u3 += Greg[3][cc] * pv;
          }
        }
        pmat[q * 4 + 0][kt] = u0; pmat[q * 4 + 1][kt] = u1;
        pmat[q * 4 + 2][kt] = u2; pmat[q * 4 + 3][kt] = u3;
        __syncthreads();
        if (tid < 16) {
          float s = 0.f;
#pragma unroll
          for (int c = 0; c < 32; ++c) {
            const f32x4 vv = *(f32x4*)&pmat[tid][c * 4];
            s += vv[0] + vv[1] + vv[2] + vv[3];
          }
          const int jl = w * 16 + tid;
          const float pv = ldsA[SWZC(jl >> 2) * 4 + (jl & 3)];
          staf(&nbuf[(gen + 1) & 1][jl], rho * s + sig * pv);
        }
        publish();
      } else {
        publish();                 // cg==15: flag only
      }
    }

    if (admm < N_ADMM - 1) {
      // ---- A': ztilde = A xt (stream own 8 rows); z/y/x; publish u ----------
#pragma unroll
      for (int r = 0; r < 8; ++r) {
        const float* ap = A + (size_t)(w * 8 + r) * NDIM + j0;
        const f32x4 a = ntf4(ap), b = ntf4(ap + 4);
        float s = a[0] * xt8[0] + a[1] * xt8[1] + a[2] * xt8[2] + a[3] * xt8[3]
                + b[0] * xt8[4] + b[1] * xt8[5] + b[2] * xt8[6] + b[3] * xt8[7];
        s = wred64(s);
        if (lane == 0) dred8[wv][r] = s;
      }
      __syncthreads();
      if (tid < 8) {
        float zt = 0.f;
#pragma unroll
        for (int qq = 0; qq < 8; ++qq) zt += dred8[qq][tid];
        zt = al * zt + (1.f - al) * mzb[tid];
        float zn = fminf(fmaxf(zt + myb[tid] / rho, mlb[tid]), mub[tid]);
        const float yn = myb[tid] + rho * (zt - zn);
        mzb[tid] = zn; myb[tid] = yn;
        staf(&u_g[w * 8 + tid], rho * zn - yn);
      }
#pragma unroll
      for (int e = 0; e < 8; ++e) x8[e] = al * xt8[e] + (1.f - al) * x8[e];
      publish();

      // ---- B: r0 = sig*x - cs + A^T u - (rho*G xt + sig*xt); publish r0 -----
      wait_prod(gen);              // u producers (group-aligned)
      {
        const f32x4 uv = ntf4(&u_g[tid * 4]);
        *(f32x4*)&ldsB[tid * 4] = uv;                  // u_lds (linear)
        f32x4 v0, v1;
#pragma unroll
        for (int e = 0; e < 4; ++e) { v0[e] = xt8[e]; v1[e] = xt8[4 + e]; }
        *(f32x4*)&ldsA[SWZC(2 * tid) * 4]     = v0;    // xt stage (swz)
        *(f32x4*)&ldsA[SWZC(2 * tid + 1) * 4] = v1;
        if ((tid >> 1) == w) {
          const int b = (tid & 1) * 8;
#pragma unroll
          for (int e = 0; e < 8; ++e) xchunk[b + e] = x8[e];
        }
      }
      __syncthreads();
      {
        // SR partial: col w*16+gl, rows gg*64..+63  (A col-slice streamed)
        float pr = 0.f;
        const float* acp = A + (size_t)(gg * 64) * NDIM + w * 16 + gl;
#pragma unroll 8
        for (int ii = 0; ii < 64; ++ii)
          pr += ntf(acp + (size_t)ii * NDIM) * ldsB[gg * 64 + ii];
        sredA[gg][gl] = pr;
        // G * xt
        float u0 = 0.f, u1 = 0.f, u2 = 0.f, u3 = 0.f;
#pragma unroll
        for (int c4 = 0; c4 < 8; ++c4) {
          const f32x4 kv = *(f32x4*)&ldsA[SWZC(kt * 8 + c4) * 4];
#pragma unroll
          for (int e = 0; e < 4; ++e) {
            const float pv = kv[e];
            const int cc = c4 * 4 + e;
            u0 += Greg[0][cc] * pv; u1 += Greg[1][cc] * pv;
            u2 += Greg[2][cc] * pv; u3 += Greg[3][cc] * pv;
          }
        }
        pmat[q * 4 + 0][kt] = u0; pmat[q * 4 + 1][kt] = u1;
        pmat[q * 4 + 2][kt] = u2; pmat[q * 4 + 3][kt] = u3;
      }
      __syncthreads();
      if (tid < 16) {
        float SR = 0.f;
#pragma unroll
        for (int g32 = 0; g32 < 32; ++g32) SR += sredA[g32][tid];
        float gx = 0.f;
#pragma unroll
        for (int c = 0; c < 32; ++c) {
          const f32x4 vv = *(f32x4*)&pmat[tid][c * 4];
          gx += vv[0] + vv[1] + vv[2] + vv[3];
        }
        const int jl = w * 16 + tid;
        const float xtv = ldsA[SWZC(jl >> 2) * 4 + (jl & 3)];
        const float right = sig * xchunk[tid] - cs_lds[tid] + SR;
        const float Kxt = rho * gx + sig * xtv;
        staf(&nbuf[(gen + 1) & 1][jl], right - Kxt);
      }
      publish();
    }
  }

  // ---------------- output: out = (al*xt + (1-al)*x) * d / gb ------------------
  if ((tid >> 1) == w) {
    const int b = (tid & 1) * 8;
#pragma unroll
    for (int e = 0; e < 8; ++e) {
      const int j = w * 16 + b + e;
      const float xf = al * xt8[e] + (1.f - al) * x8[e];
      out[j] = xf * dvec[j] / gb;
    }
  }
}

extern "C" void kernel_launch(void* const* d_in, const int* in_sizes, int n_in,
                              void* d_out, int out_size, void* d_ws, size_t ws_size,
                              hipStream_t stream) {
  const float* A   = (const float*)d_in[0];
  const float* c   = (const float*)d_in[1];
  const float* lb  = (const float*)d_in[2];
  const float* ub  = (const float*)d_in[3];
  const float* dv  = (const float*)d_in[4];
  const float* ev  = (const float*)d_in[5];
  const float* gc  = (const float*)d_in[6];
  const float* gb  = (const float*)d_in[7];
  const float* rho = (const float*)d_in[8];
  const float* sg  = (const float*)d_in[9];
  const float* al  = (const float*)d_in[10];
  float* out = (float*)d_out;
  unsigned char* ws = (unsigned char*)d_ws;

  // zero kill + flag slots (data buffers start at 49152; all data reads gated)
  (void)hipMemsetAsync(d_ws, 0, 32768, stream);

  admm_lp_kernel<<<dim3(NWG), dim3(NT), 0, stream>>>(
      A, c, lb, ub, dv, ev, gc, gb, rho, sg, al, out, ws);
}

// Round 14
// 27100.064 us; speedup vs baseline: 1.0007x; 1.0007x over previous
//
#include <hip/hip_runtime.h>

#define NWG 256
#define NT  512
#define NDIM 4096
#define MROWS 2048
#define N_ADMM 30
#define N_CG 15

typedef unsigned long long ull;
typedef float f32x4 __attribute__((ext_vector_type(4)));

// 16B-chunk XOR swizzle: breaks the stride-128B -> same-bank pattern of the
// G-mult ds_read_b128s (bank = chunk%8; xor with chunk>>3 spreads 8 ways).
#define SWZC(c) ((c) ^ (((c) >> 3) & 7))

__device__ __forceinline__ float wred64(float v) {
#pragma unroll
  for (int m = 32; m > 0; m >>= 1) v += __shfl_xor(v, m, 64);
  return v;
}
__device__ __forceinline__ void sta32(unsigned* p, unsigned v) {
  __hip_atomic_store(p, v, __ATOMIC_RELAXED, __HIP_MEMORY_SCOPE_AGENT);
}
__device__ __forceinline__ unsigned lda32(const unsigned* p) {
  return __hip_atomic_load(p, __ATOMIC_RELAXED, __HIP_MEMORY_SCOPE_AGENT);
}
__device__ __forceinline__ void staf(float* p, float v) {
  __hip_atomic_store((unsigned*)p, __float_as_uint(v), __ATOMIC_RELAXED,
                     __HIP_MEMORY_SCOPE_AGENT);
}
__device__ __forceinline__ f32x4 ntf4(const float* p) {
  return __builtin_nontemporal_load((const f32x4*)p);
}
__device__ __forceinline__ float ntf(const float* p) {
  return __builtin_nontemporal_load(p);
}

// -------- workspace layout --------------------------------------------------
#define WS_KILL 128
#define WS_FLAG 8192     // 256 slots x 64B, uint gen (payload-free, monotone)
#define WS_NB0  49152    // n-space exchange bank0: 4096 f32 (Kp / r0 / Gdiag)
#define WS_NB1  65536    // bank1 (gen-parity ping-pong)
#define WS_U    81920    // m-space u: 2048 f32 (single buffer; WAR-safe by gates)

// ONE WG PER CU (grid=256): min-waves=1 -> 256 VGPR budget so Greg[4][32]
// (128 VGPR) stays in registers. R13's (NT,2) capped at 128 VGPR -> full spill.
__global__ __launch_bounds__(NT, 1)
void admm_lp_kernel(const float* __restrict__ A, const float* __restrict__ cvec,
                    const float* __restrict__ lbv, const float* __restrict__ ubv,
                    const float* __restrict__ dvec, const float* __restrict__ evec,
                    const float* __restrict__ gcp, const float* __restrict__ gbp,
                    const float* __restrict__ rhop, const float* __restrict__ sigp,
                    const float* __restrict__ alp,
                    float* __restrict__ out, unsigned char* __restrict__ ws)
{
  const int tid = threadIdx.x;
  const int w = blockIdx.x;
  const int wv = tid >> 6, lane = tid & 63;
  const int j0 = tid * 8;          // this thread's 8-element n-space slice
  const int q  = tid >> 7;         // G row-quad 0..3 (rows w*16+q*4 .. +3)
  const int kt = tid & 127;        // G k-thread (cols kt*32 .. +31)
  const int gg = tid >> 4, gl = tid & 15;   // B-phase col-slice mapping

  unsigned* kill  = (unsigned*)(ws + WS_KILL);
  unsigned* flags = (unsigned*)(ws + WS_FLAG);
  float* nbuf[2] = { (float*)(ws + WS_NB0), (float*)(ws + WS_NB1) };
  float* u_g = (float*)(ws + WS_U);

  __shared__ float s_scal[8];
  __shared__ float dredA[8], dredB[8];
  __shared__ float dred8[8][8];
  __shared__ float sredA[32][16];
  __shared__ float pmat[16][132];            // padded: 16-thread reduce 2-way banks
  __shared__ float cs_lds[16], xchunk[16], diag16[16];
  __shared__ float mzb[8], myb[8], mlb[8], mub[8];
  __shared__ int s_dead;
  __shared__ float ldsA[4096];   // swizzled: p/xt stage (CG); GEMM buf A
  __shared__ float ldsB[4096];   // GEMM buf B; B-phase u_lds (first 2048, linear)

  float Greg[4][32];             // G[w*16+q*4+rr][kt*32+cc]  (128 VGPR)
  float p8[8], r8[8], xt8[8], x8[8], Md8[8];
  unsigned gen = 0;

  // one-hop producer wait: wave v's data comes from producers v*32..v*32+31
  // (holds for Kp/r0/diag n-slices AND the B-phase u rows). Flags are
  // payload-free monotone gens -> single bank, overwrite-with-larger is safe.
  auto wait_prod = [&](unsigned G) {
    if (s_dead) return;
    unsigned* fp = &flags[(size_t)(wv * 32 + (lane & 31)) * 16];
    int spin = 0;
    for (;;) {
      unsigned v = lda32(fp);
      if (__all(v >= G)) break;
      __builtin_amdgcn_s_sleep(1);
      if ((++spin & 127) == 0) {
        if (lda32(kill) != 0u || spin > 2000000) {
          s_dead = 1; sta32(kill, 1u); break;
        }
      }
    }
    asm volatile("" ::: "memory");
    __builtin_amdgcn_sched_barrier(0);
  };

  // all exchange-data stores are wave0 (tid<16 / tid<8) -> wave0's vmcnt(0)
  // drains them before the flag store. ++gen uniform across all threads.
  auto publish = [&]() {
    if (wv == 0) {
      asm volatile("s_waitcnt vmcnt(0)" ::: "memory");
      __builtin_amdgcn_sched_barrier(0);
      if (lane == 0 && !s_dead) sta32(&flags[(size_t)w * 16], gen + 1);
    }
    ++gen;
  };

  // ---------------- prologue: scalars, m-state, G = A^T A (own 16 rows) -------
  if (tid == 0) {
    s_scal[0] = sigp[0]; s_scal[1] = rhop[0]; s_scal[2] = alp[0];
    s_scal[3] = gcp[0];  s_scal[4] = gbp[0];
    s_dead = 0;
  }
  __syncthreads();
  const float sig = s_scal[0], rho = s_scal[1], al = s_scal[2];
  const float gc = s_scal[3], gb = s_scal[4];

  if (tid < 8) {
    const int rm = w * 8 + tid;
    mzb[tid] = 0.f; myb[tid] = 0.f;
    const float ee = evec[rm];
    mlb[tid] = gb * ee * lbv[rm];
    mub[tid] = gb * ee * ubv[rm];
  }
  if (tid < 16) {
    const int j = w * 16 + tid;
    cs_lds[tid] = gc * dvec[j] * cvec[j];
  }

#pragma unroll
  for (int rr = 0; rr < 4; ++rr)
#pragma unroll
    for (int cc = 0; cc < 32; ++cc) Greg[rr][cc] = 0.f;

  // software-pipelined row stream: LDS double-buffer + register prefetch
  {
    f32x4 pf0 = ntf4(A + j0), pf1 = ntf4(A + j0 + 4);        // row 0
    *(f32x4*)&ldsA[SWZC(2 * tid) * 4]     = pf0;
    *(f32x4*)&ldsA[SWZC(2 * tid + 1) * 4] = pf1;
    pf0 = ntf4(A + NDIM + j0); pf1 = ntf4(A + NDIM + j0 + 4); // row 1
    __syncthreads();
    float* bc = ldsA;
    float* bn = ldsB;
#pragma unroll 1
    for (int i = 0; i < MROWS; ++i) {
      if (i + 1 < MROWS) {
        *(f32x4*)&bn[SWZC(2 * tid) * 4]     = pf0;
        *(f32x4*)&bn[SWZC(2 * tid + 1) * 4] = pf1;
      }
      if (i + 2 < MROWS) {
        pf0 = ntf4(A + (size_t)(i + 2) * NDIM + j0);
        pf1 = ntf4(A + (size_t)(i + 2) * NDIM + j0 + 4);
      }
      const f32x4 av = *(f32x4*)&bc[SWZC(w * 4 + q) * 4];   // A[i, own 4 rows]
#pragma unroll
      for (int c4 = 0; c4 < 8; ++c4) {
        const f32x4 kv = *(f32x4*)&bc[SWZC(kt * 8 + c4) * 4];
#pragma unroll
        for (int e = 0; e < 4; ++e) {
          const float kvv = kv[e];
          const int cc = c4 * 4 + e;
          Greg[0][cc] += av.x * kvv;
          Greg[1][cc] += av.y * kvv;
          Greg[2][cc] += av.z * kvv;
          Greg[3][cc] += av.w * kvv;
        }
      }
      __syncthreads();
      float* t = bc; bc = bn; bn = t;
    }
  }

  // G diagonal -> Md (one exchange): row j=w*16+q*4+rr sits at kt=w>>1,
  // cc=(w&1)*16+q*4+rr
  if (kt == (w >> 1)) {
#pragma unroll
    for (int rr = 0; rr < 4; ++rr)
      diag16[q * 4 + rr] = Greg[rr][(w & 1) * 16 + q * 4 + rr];
  }
  __syncthreads();
  if (tid < 16) staf(&nbuf[1][w * 16 + tid], diag16[tid]);
  publish();                       // gen 1
  wait_prod(gen);
  {
    const f32x4 d0 = ntf4(&nbuf[1][j0]), d1 = ntf4(&nbuf[1][j0 + 4]);
#pragma unroll
    for (int e = 0; e < 4; ++e) { Md8[e] = sig + rho * d0[e]; Md8[4 + e] = sig + rho * d1[e]; }
  }
#pragma unroll
  for (int e = 0; e < 8; ++e) { xt8[e] = 0.f; x8[e] = 0.f; }

  float rz = 1.f;

  // ---------------- main loop --------------------------------------------------
#pragma unroll 1
  for (int admm = 0; admm < N_ADMM; ++admm) {
#pragma unroll 1
    for (int cg = 0; cg <= N_CG; ++cg) {
      if (cg == 0) {
        // ---- acquire r0; z=r/Md; rz; p=z -------------------------------------
        if (admm == 0) {
          const f32x4 dv0 = ntf4(dvec + j0), dv1 = ntf4(dvec + j0 + 4);
          const f32x4 cv0 = ntf4(cvec + j0), cv1 = ntf4(cvec + j0 + 4);
#pragma unroll
          for (int e = 0; e < 4; ++e) {
            r8[e]     = -gc * dv0[e] * cv0[e];
            r8[4 + e] = -gc * dv1[e] * cv1[e];
          }
        } else {
          wait_prod(gen);
          const f32x4 a = ntf4(&nbuf[gen & 1][j0]), b = ntf4(&nbuf[gen & 1][j0 + 4]);
#pragma unroll
          for (int e = 0; e < 4; ++e) { r8[e] = a[e]; r8[4 + e] = b[e]; }
        }
        float z8[8], part = 0.f;
#pragma unroll
        for (int e = 0; e < 8; ++e) { z8[e] = r8[e] / Md8[e]; part += r8[e] * z8[e]; }
        part = wred64(part);
        if (lane == 0) dredA[wv] = part;
        __syncthreads();
        rz = dredA[0] + dredA[1] + dredA[2] + dredA[3]
           + dredA[4] + dredA[5] + dredA[6] + dredA[7];
#pragma unroll
        for (int e = 0; e < 8; ++e) p8[e] = z8[e];
      } else {
        // ---- acquire Kp; alpha; xt; (r,z,rz,beta,p unless last) --------------
        wait_prod(gen);
        const f32x4 a = ntf4(&nbuf[gen & 1][j0]), b = ntf4(&nbuf[gen & 1][j0 + 4]);
        float Kp8[8];
#pragma unroll
        for (int e = 0; e < 4; ++e) { Kp8[e] = a[e]; Kp8[4 + e] = b[e]; }
        float part = 0.f;
#pragma unroll
        for (int e = 0; e < 8; ++e) part += p8[e] * Kp8[e];
        part = wred64(part);
        if (lane == 0) dredA[wv] = part;
        __syncthreads();
        const float pKp = dredA[0] + dredA[1] + dredA[2] + dredA[3]
                        + dredA[4] + dredA[5] + dredA[6] + dredA[7];
        const float alpha = rz / pKp;
#pragma unroll
        for (int e = 0; e < 8; ++e) xt8[e] += alpha * p8[e];
        if (cg < N_CG) {
          float z8[8], pb = 0.f;
#pragma unroll
          for (int e = 0; e < 8; ++e) {
            r8[e] -= alpha * Kp8[e];
            z8[e] = r8[e] / Md8[e];
            pb += r8[e] * z8[e];
          }
          pb = wred64(pb);
          if (lane == 0) dredB[wv] = pb;
          __syncthreads();
          const float rzn = dredB[0] + dredB[1] + dredB[2] + dredB[3]
                          + dredB[4] + dredB[5] + dredB[6] + dredB[7];
          const float beta = rzn / rz;
          rz = rzn;
#pragma unroll
          for (int e = 0; e < 8; ++e) p8[e] = z8[e] + beta * p8[e];
        }
      }
      if (cg < N_CG) {
        // ---- Kp_next = rho*(G p) + sig*p on own 16; publish 64 B -------------
        {
          f32x4 v0, v1;
#pragma unroll
          for (int e = 0; e < 4; ++e) { v0[e] = p8[e]; v1[e] = p8[4 + e]; }
          *(f32x4*)&ldsA[SWZC(2 * tid) * 4]     = v0;
          *(f32x4*)&ldsA[SWZC(2 * tid + 1) * 4] = v1;
        }
        __syncthreads();
        float u0 = 0.f, u1 = 0.f, u2 = 0.f, u3 = 0.f;
#pragma unroll
        for (int c4 = 0; c4 < 8; ++c4) {
          const f32x4 kv = *(f32x4*)&ldsA[SWZC(kt * 8 + c4) * 4];
#pragma unroll
          for (int e = 0; e < 4; ++e) {
            const float pv = kv[e];
            const int cc = c4 * 4 + e;
            u0 += Greg[0][cc] * pv; u1 += Greg[1][cc] * pv;
            u2 += Greg[2][cc] * pv; u3 += Greg[3][cc] * pv;
          }
        }
        pmat[q * 4 + 0][kt] = u0; pmat[q * 4 + 1][kt] = u1;
        pmat[q * 4 + 2][kt] = u2; pmat[q * 4 + 3][kt] = u3;
        __syncthreads();
        if (tid < 16) {
          float s = 0.f;
#pragma unroll
          for (int c = 0; c < 32; ++c) {
            const f32x4 vv = *(f32x4*)&pmat[tid][c * 4];
            s += vv[0] + vv[1] + vv[2] + vv[3];
          }
          const int jl = w * 16 + tid;
          const float pv = ldsA[SWZC(jl >> 2) * 4 + (jl & 3)];
          staf(&nbuf[(gen + 1) & 1][jl], rho * s + sig * pv);
        }
        publish();
      } else {
        publish();                 // cg==15: flag only
      }
    }

    if (admm < N_ADMM - 1) {
      // ---- A': ztilde = A xt (stream own 8 rows); z/y/x; publish u ----------
#pragma unroll
      for (int r = 0; r < 8; ++r) {
        const float* ap = A + (size_t)(w * 8 + r) * NDIM + j0;
        const f32x4 a = ntf4(ap), b = ntf4(ap + 4);
        float s = a[0] * xt8[0] + a[1] * xt8[1] + a[2] * xt8[2] + a[3] * xt8[3]
                + b[0] * xt8[4] + b[1] * xt8[5] + b[2] * xt8[6] + b[3] * xt8[7];
        s = wred64(s);
        if (lane == 0) dred8[wv][r] = s;
      }
      __syncthreads();
      if (tid < 8) {
        float zt = 0.f;
#pragma unroll
        for (int qq = 0; qq < 8; ++qq) zt += dred8[qq][tid];
        zt = al * zt + (1.f - al) * mzb[tid];
        float zn = fminf(fmaxf(zt + myb[tid] / rho, mlb[tid]), mub[tid]);
        const float yn = myb[tid] + rho * (zt - zn);
        mzb[tid] = zn; myb[tid] = yn;
        staf(&u_g[w * 8 + tid], rho * zn - yn);
      }
#pragma unroll
      for (int e = 0; e < 8; ++e) x8[e] = al * xt8[e] + (1.f - al) * x8[e];
      publish();

      // ---- B: r0 = sig*x - cs + A^T u - (rho*G xt + sig*xt); publish r0 -----
      wait_prod(gen);              // u producers (group-aligned)
      {
        const f32x4 uv = ntf4(&u_g[tid * 4]);
        *(f32x4*)&ldsB[tid * 4] = uv;                  // u_lds (linear)
        f32x4 v0, v1;
#pragma unroll
        for (int e = 0; e < 4; ++e) { v0[e] = xt8[e]; v1[e] = xt8[4 + e]; }
        *(f32x4*)&ldsA[SWZC(2 * tid) * 4]     = v0;    // xt stage (swz)
        *(f32x4*)&ldsA[SWZC(2 * tid + 1) * 4] = v1;
        if ((tid >> 1) == w) {
          const int b = (tid & 1) * 8;
#pragma unroll
          for (int e = 0; e < 8; ++e) xchunk[b + e] = x8[e];
        }
      }
      __syncthreads();
      {
        // SR partial: col w*16+gl, rows gg*64..+63  (A col-slice streamed)
        float pr = 0.f;
        const float* acp = A + (size_t)(gg * 64) * NDIM + w * 16 + gl;
#pragma unroll 8
        for (int ii = 0; ii < 64; ++ii)
          pr += ntf(acp + (size_t)ii * NDIM) * ldsB[gg * 64 + ii];
        sredA[gg][gl] = pr;
        // G * xt
        float u0 = 0.f, u1 = 0.f, u2 = 0.f, u3 = 0.f;
#pragma unroll
        for (int c4 = 0; c4 < 8; ++c4) {
          const f32x4 kv = *(f32x4*)&ldsA[SWZC(kt * 8 + c4) * 4];
#pragma unroll
          for (int e = 0; e < 4; ++e) {
            const float pv = kv[e];
            const int cc = c4 * 4 + e;
            u0 += Greg[0][cc] * pv; u1 += Greg[1][cc] * pv;
            u2 += Greg[2][cc] * pv; u3 += Greg[3][cc] * pv;
          }
        }
        pmat[q * 4 + 0][kt] = u0; pmat[q * 4 + 1][kt] = u1;
        pmat[q * 4 + 2][kt] = u2; pmat[q * 4 + 3][kt] = u3;
      }
      __syncthreads();
      if (tid < 16) {
        float SR = 0.f;
#pragma unroll
        for (int g32 = 0; g32 < 32; ++g32) SR += sredA[g32][tid];
        float gx = 0.f;
#pragma unroll
        for (int c = 0; c < 32; ++c) {
          const f32x4 vv = *(f32x4*)&pmat[tid][c * 4];
          gx += vv[0] + vv[1] + vv[2] + vv[3];
        }
        const int jl = w * 16 + tid;
        const float xtv = ldsA[SWZC(jl >> 2) * 4 + (jl & 3)];
        const float right = sig * xchunk[tid] - cs_lds[tid] + SR;
        const float Kxt = rho * gx + sig * xtv;
        staf(&nbuf[(gen + 1) & 1][jl], right - Kxt);
      }
      publish();
    }
  }

  // ---------------- output: out = (al*xt + (1-al)*x) * d / gb ------------------
  if ((tid >> 1) == w) {
    const int b = (tid & 1) * 8;
#pragma unroll
    for (int e = 0; e < 8; ++e) {
      const int j = w * 16 + b + e;
      const float xf = al * xt8[e] + (1.f - al) * x8[e];
      out[j] = xf * dvec[j] / gb;
    }
  }
}

extern "C" void kernel_launch(void* const* d_in, const int* in_sizes, int n_in,
                              void* d_out, int out_size, void* d_ws, size_t ws_size,
                              hipStream_t stream) {
  const float* A   = (const float*)d_in[0];
  const float* c   = (const float*)d_in[1];
  const float* lb  = (const float*)d_in[2];
  const float* ub  = (const float*)d_in[3];
  const float* dv  = (const float*)d_in[4];
  const float* ev  = (const float*)d_in[5];
  const float* gc  = (const float*)d_in[6];
  const float* gb  = (const float*)d_in[7];
  const float* rho = (const float*)d_in[8];
  const float* sg  = (const float*)d_in[9];
  const float* al  = (const float*)d_in[10];
  float* out = (float*)d_out;
  unsigned char* ws = (unsigned char*)d_ws;

  // zero kill + flag slots (data buffers start at 49152; all data reads gated)
  (void)hipMemsetAsync(d_ws, 0, 32768, stream);

  admm_lp_kernel<<<dim3(NWG), dim3(NT), 0, stream>>>(
      A, c, lb, ub, dv, ev, gc, gb, rho, sg, al, out, ws);
}

// Round 15
// 5584.616 us; speedup vs baseline: 4.8562x; 4.8526x over previous
//
#include <hip/hip_runtime.h>

#define NWG 256
#define NT  512
#define NDIM 4096
#define MROWS 2048
#define N_ADMM 30
#define N_CG 15

typedef unsigned long long ull;
typedef float f32x4 __attribute__((ext_vector_type(4)));

// 16B-chunk XOR swizzle: breaks the stride-128B -> same-bank pattern of the
// G-mult ds_read_b128s (bank = chunk%8; xor with chunk>>3 spreads 8 ways).
#define SWZC(c) ((c) ^ (((c) >> 3) & 7))

__device__ __forceinline__ float wred64(float v) {
#pragma unroll
  for (int m = 32; m > 0; m >>= 1) v += __shfl_xor(v, m, 64);
  return v;
}
__device__ __forceinline__ void sta32(unsigned* p, unsigned v) {
  __hip_atomic_store(p, v, __ATOMIC_RELAXED, __HIP_MEMORY_SCOPE_AGENT);
}
__device__ __forceinline__ unsigned lda32(const unsigned* p) {
  return __hip_atomic_load(p, __ATOMIC_RELAXED, __HIP_MEMORY_SCOPE_AGENT);
}
__device__ __forceinline__ void staf(float* p, float v) {
  __hip_atomic_store((unsigned*)p, __float_as_uint(v), __ATOMIC_RELAXED,
                     __HIP_MEMORY_SCOPE_AGENT);
}
__device__ __forceinline__ f32x4 ntf4(const float* p) {
  return __builtin_nontemporal_load((const f32x4*)p);
}
__device__ __forceinline__ float ntf(const float* p) {
  return __builtin_nontemporal_load(p);
}

// -------- workspace layout --------------------------------------------------
#define WS_KILL 128
#define WS_FLAG 8192     // 256 slots x 64B, uint gen (payload-free, monotone)
#define WS_NB0  49152    // n-space exchange bank0: 4096 f32 (Kp / r0 / Gdiag)
#define WS_NB1  65536    // bank1 (gen-parity ping-pong)
#define WS_U    81920    // m-space u: 2048 f32 (single buffer; WAR-safe by gates)

// ONE WG PER CU (grid=256). All Greg accesses are compile-time-static (rule:
// a single runtime-indexed access sends the whole array to scratch -- R13/R14's
// 142 GB HBM bug was the diag extraction's runtime column index).
__global__ __launch_bounds__(NT, 1)
void admm_lp_kernel(const float* __restrict__ A, const float* __restrict__ cvec,
                    const float* __restrict__ lbv, const float* __restrict__ ubv,
                    const float* __restrict__ dvec, const float* __restrict__ evec,
                    const float* __restrict__ gcp, const float* __restrict__ gbp,
                    const float* __restrict__ rhop, const float* __restrict__ sigp,
                    const float* __restrict__ alp,
                    float* __restrict__ out, unsigned char* __restrict__ ws)
{
  const int tid = threadIdx.x;
  const int w = blockIdx.x;
  const int wv = tid >> 6, lane = tid & 63;
  const int j0 = tid * 8;          // this thread's 8-element n-space slice
  const int q  = tid >> 7;         // G row-quad 0..3 (rows w*16+q*4 .. +3)
  const int kt = tid & 127;        // G k-thread (cols kt*32 .. +31)
  const int gg = tid >> 4, gl = tid & 15;   // B-phase col-slice mapping

  unsigned* kill  = (unsigned*)(ws + WS_KILL);
  unsigned* flags = (unsigned*)(ws + WS_FLAG);
  float* nb0 = (float*)(ws + WS_NB0);
  float* nb1 = (float*)(ws + WS_NB1);
  float* u_g = (float*)(ws + WS_U);

  __shared__ float s_scal[8];
  __shared__ float dredA[8], dredB[8];
  __shared__ float dred8[8][8];
  __shared__ float sredA[32][16];
  __shared__ float pmat[16][132];            // padded: 16-thread reduce 2-way banks
  __shared__ float cs_lds[16], xchunk[16], diag16[16];
  __shared__ float mzb[8], myb[8], mlb[8], mub[8];
  __shared__ int s_dead;
  __shared__ float ldsA[4096];   // swizzled: p/xt stage (CG); GEMM buf A
  __shared__ float ldsB[4096];   // GEMM buf B; B-phase u_lds (first 2048, linear)

  float Greg[4][32];             // G[w*16+q*4+rr][kt*32+cc]  (128 VGPR)
  float p8[8], r8[8], xt8[8], x8[8], Md8[8];
  unsigned gen = 0;

  // one-hop producer wait: wave v's data comes from producers v*32..v*32+31
  auto wait_prod = [&](unsigned G) {
    if (s_dead) return;
    unsigned* fp = &flags[(size_t)(wv * 32 + (lane & 31)) * 16];
    int spin = 0;
    for (;;) {
      unsigned v = lda32(fp);
      if (__all(v >= G)) break;
      __builtin_amdgcn_s_sleep(1);
      if ((++spin & 127) == 0) {
        if (lda32(kill) != 0u || spin > 2000000) {
          s_dead = 1; sta32(kill, 1u); break;
        }
      }
    }
    asm volatile("" ::: "memory");
    __builtin_amdgcn_sched_barrier(0);
  };

  // all exchange-data stores are wave0 (tid<16 / tid<8) -> wave0's vmcnt(0)
  // drains them before the flag store. ++gen uniform across all threads.
  auto publish = [&]() {
    if (wv == 0) {
      asm volatile("s_waitcnt vmcnt(0)" ::: "memory");
      __builtin_amdgcn_sched_barrier(0);
      if (lane == 0 && !s_dead) sta32(&flags[(size_t)w * 16], gen + 1);
    }
    ++gen;
  };

  // ---------------- prologue: scalars, m-state, G = A^T A (own 16 rows) -------
  if (tid == 0) {
    s_scal[0] = sigp[0]; s_scal[1] = rhop[0]; s_scal[2] = alp[0];
    s_scal[3] = gcp[0];  s_scal[4] = gbp[0];
    s_dead = 0;
  }
  __syncthreads();
  const float sig = s_scal[0], rho = s_scal[1], al = s_scal[2];
  const float gc = s_scal[3], gb = s_scal[4];

  if (tid < 8) {
    const int rm = w * 8 + tid;
    mzb[tid] = 0.f; myb[tid] = 0.f;
    const float ee = evec[rm];
    mlb[tid] = gb * ee * lbv[rm];
    mub[tid] = gb * ee * ubv[rm];
  }
  if (tid < 16) {
    const int j = w * 16 + tid;
    cs_lds[tid] = gc * dvec[j] * cvec[j];
  }

#pragma unroll
  for (int rr = 0; rr < 4; ++rr)
#pragma unroll
    for (int cc = 0; cc < 32; ++cc) Greg[rr][cc] = 0.f;

  // software-pipelined row stream: LDS double-buffer + register prefetch
  {
    f32x4 pf0 = ntf4(A + j0), pf1 = ntf4(A + j0 + 4);        // row 0
    *(f32x4*)&ldsA[SWZC(2 * tid) * 4]     = pf0;
    *(f32x4*)&ldsA[SWZC(2 * tid + 1) * 4] = pf1;
    pf0 = ntf4(A + NDIM + j0); pf1 = ntf4(A + NDIM + j0 + 4); // row 1
    __syncthreads();
    float* bc = ldsA;
    float* bn = ldsB;
#pragma unroll 1
    for (int i = 0; i < MROWS; ++i) {
      if (i + 1 < MROWS) {
        *(f32x4*)&bn[SWZC(2 * tid) * 4]     = pf0;
        *(f32x4*)&bn[SWZC(2 * tid + 1) * 4] = pf1;
      }
      if (i + 2 < MROWS) {
        pf0 = ntf4(A + (size_t)(i + 2) * NDIM + j0);
        pf1 = ntf4(A + (size_t)(i + 2) * NDIM + j0 + 4);
      }
      const f32x4 av = *(f32x4*)&bc[SWZC(w * 4 + q) * 4];   // A[i, own 4 rows]
#pragma unroll
      for (int c4 = 0; c4 < 8; ++c4) {
        const f32x4 kv = *(f32x4*)&bc[SWZC(kt * 8 + c4) * 4];
#pragma unroll
        for (int e = 0; e < 4; ++e) {
          const float kvv = kv[e];
          const int cc = c4 * 4 + e;
          Greg[0][cc] += av.x * kvv;
          Greg[1][cc] += av.y * kvv;
          Greg[2][cc] += av.z * kvv;
          Greg[3][cc] += av.w * kvv;
        }
      }
      __syncthreads();
      float* t = bc; bc = bn; bn = t;
    }
  }

  // G diagonal -> Md: row j=w*16+q*4+rr sits at kt=w>>1, cc=(w&1)*16+q*4+rr.
  // STATIC-INDEX extraction: unrolled compare-select keeps Greg in registers.
  if (kt == (w >> 1)) {
#pragma unroll
    for (int rr = 0; rr < 4; ++rr) {
      const int tc = (w & 1) * 16 + q * 4 + rr;   // runtime target
      float dv = 0.f;
#pragma unroll
      for (int cc = 0; cc < 32; ++cc)
        dv = (cc == tc) ? Greg[rr][cc] : dv;      // all Greg indices static
      diag16[q * 4 + rr] = dv;
    }
  }
  __syncthreads();
  if (tid < 16) staf(&nb1[w * 16 + tid], diag16[tid]);
  publish();                       // gen 1
  wait_prod(gen);
  {
    const f32x4 d0 = ntf4(&nb1[j0]), d1 = ntf4(&nb1[j0 + 4]);
#pragma unroll
    for (int e = 0; e < 4; ++e) { Md8[e] = sig + rho * d0[e]; Md8[4 + e] = sig + rho * d1[e]; }
  }
#pragma unroll
  for (int e = 0; e < 8; ++e) { xt8[e] = 0.f; x8[e] = 0.f; }

  float rz = 1.f;

  // ---------------- main loop --------------------------------------------------
#pragma unroll 1
  for (int admm = 0; admm < N_ADMM; ++admm) {
#pragma unroll 1
    for (int cg = 0; cg <= N_CG; ++cg) {
      if (cg == 0) {
        // ---- acquire r0; z=r/Md; rz; p=z -------------------------------------
        if (admm == 0) {
          const f32x4 dv0 = ntf4(dvec + j0), dv1 = ntf4(dvec + j0 + 4);
          const f32x4 cv0 = ntf4(cvec + j0), cv1 = ntf4(cvec + j0 + 4);
#pragma unroll
          for (int e = 0; e < 4; ++e) {
            r8[e]     = -gc * dv0[e] * cv0[e];
            r8[4 + e] = -gc * dv1[e] * cv1[e];
          }
        } else {
          wait_prod(gen);
          const float* nb = (gen & 1) ? nb1 : nb0;
          const f32x4 a = ntf4(nb + j0), b = ntf4(nb + j0 + 4);
#pragma unroll
          for (int e = 0; e < 4; ++e) { r8[e] = a[e]; r8[4 + e] = b[e]; }
        }
        float z8[8], part = 0.f;
#pragma unroll
        for (int e = 0; e < 8; ++e) { z8[e] = r8[e] / Md8[e]; part += r8[e] * z8[e]; }
        part = wred64(part);
        if (lane == 0) dredA[wv] = part;
        __syncthreads();
        rz = dredA[0] + dredA[1] + dredA[2] + dredA[3]
           + dredA[4] + dredA[5] + dredA[6] + dredA[7];
#pragma unroll
        for (int e = 0; e < 8; ++e) p8[e] = z8[e];
      } else {
        // ---- acquire Kp; alpha; xt; (r,z,rz,beta,p unless last) --------------
        wait_prod(gen);
        const float* nb = (gen & 1) ? nb1 : nb0;
        const f32x4 a = ntf4(nb + j0), b = ntf4(nb + j0 + 4);
        float Kp8[8];
#pragma unroll
        for (int e = 0; e < 4; ++e) { Kp8[e] = a[e]; Kp8[4 + e] = b[e]; }
        float part = 0.f;
#pragma unroll
        for (int e = 0; e < 8; ++e) part += p8[e] * Kp8[e];
        part = wred64(part);
        if (lane == 0) dredA[wv] = part;
        __syncthreads();
        const float pKp = dredA[0] + dredA[1] + dredA[2] + dredA[3]
                        + dredA[4] + dredA[5] + dredA[6] + dredA[7];
        const float alpha = rz / pKp;
#pragma unroll
        for (int e = 0; e < 8; ++e) xt8[e] += alpha * p8[e];
        if (cg < N_CG) {
          float z8[8], pb = 0.f;
#pragma unroll
          for (int e = 0; e < 8; ++e) {
            r8[e] -= alpha * Kp8[e];
            z8[e] = r8[e] / Md8[e];
            pb += r8[e] * z8[e];
          }
          pb = wred64(pb);
          if (lane == 0) dredB[wv] = pb;
          __syncthreads();
          const float rzn = dredB[0] + dredB[1] + dredB[2] + dredB[3]
                          + dredB[4] + dredB[5] + dredB[6] + dredB[7];
          const float beta = rzn / rz;
          rz = rzn;
#pragma unroll
          for (int e = 0; e < 8; ++e) p8[e] = z8[e] + beta * p8[e];
        }
      }
      if (cg < N_CG) {
        // ---- Kp_next = rho*(G p) + sig*p on own 16; publish 64 B -------------
        {
          f32x4 v0, v1;
#pragma unroll
          for (int e = 0; e < 4; ++e) { v0[e] = p8[e]; v1[e] = p8[4 + e]; }
          *(f32x4*)&ldsA[SWZC(2 * tid) * 4]     = v0;
          *(f32x4*)&ldsA[SWZC(2 * tid + 1) * 4] = v1;
        }
        __syncthreads();
        float u0 = 0.f, u1 = 0.f, u2 = 0.f, u3 = 0.f;
#pragma unroll
        for (int c4 = 0; c4 < 8; ++c4) {
          const f32x4 kv = *(f32x4*)&ldsA[SWZC(kt * 8 + c4) * 4];
#pragma unroll
          for (int e = 0; e < 4; ++e) {
            const float pv = kv[e];
            const int cc = c4 * 4 + e;
            u0 += Greg[0][cc] * pv; u1 += Greg[1][cc] * pv;
            u2 += Greg[2][cc] * pv; u3 += Greg[3][cc] * pv;
          }
        }
        pmat[q * 4 + 0][kt] = u0; pmat[q * 4 + 1][kt] = u1;
        pmat[q * 4 + 2][kt] = u2; pmat[q * 4 + 3][kt] = u3;
        __syncthreads();
        if (tid < 16) {
          float s = 0.f;
#pragma unroll
          for (int c = 0; c < 32; ++c) {
            const f32x4 vv = *(f32x4*)&pmat[tid][c * 4];
            s += vv[0] + vv[1] + vv[2] + vv[3];
          }
          const int jl = w * 16 + tid;
          const float pv = ldsA[SWZC(jl >> 2) * 4 + (jl & 3)];
          float* nbw = ((gen + 1) & 1) ? nb1 : nb0;
          staf(nbw + jl, rho * s + sig * pv);
        }
        publish();
      } else {
        publish();                 // cg==15: flag only
      }
    }

    if (admm < N_ADMM - 1) {
      // ---- A': ztilde = A xt (stream own 8 rows); z/y/x; publish u ----------
#pragma unroll
      for (int r = 0; r < 8; ++r) {
        const float* ap = A + (size_t)(w * 8 + r) * NDIM + j0;
        const f32x4 a = ntf4(ap), b = ntf4(ap + 4);
        float s = a[0] * xt8[0] + a[1] * xt8[1] + a[2] * xt8[2] + a[3] * xt8[3]
                + b[0] * xt8[4] + b[1] * xt8[5] + b[2] * xt8[6] + b[3] * xt8[7];
        s = wred64(s);
        if (lane == 0) dred8[wv][r] = s;
      }
      __syncthreads();
      if (tid < 8) {
        float zt = 0.f;
#pragma unroll
        for (int qq = 0; qq < 8; ++qq) zt += dred8[qq][tid];
        zt = al * zt + (1.f - al) * mzb[tid];
        float zn = fminf(fmaxf(zt + myb[tid] / rho, mlb[tid]), mub[tid]);
        const float yn = myb[tid] + rho * (zt - zn);
        mzb[tid] = zn; myb[tid] = yn;
        staf(&u_g[w * 8 + tid], rho * zn - yn);
      }
#pragma unroll
      for (int e = 0; e < 8; ++e) x8[e] = al * xt8[e] + (1.f - al) * x8[e];
      publish();

      // ---- B: r0 = sig*x - cs + A^T u - (rho*G xt + sig*xt); publish r0 -----
      wait_prod(gen);              // u producers (group-aligned)
      {
        const f32x4 uv = ntf4(&u_g[tid * 4]);
        *(f32x4*)&ldsB[tid * 4] = uv;                  // u_lds (linear)
        f32x4 v0, v1;
#pragma unroll
        for (int e = 0; e < 4; ++e) { v0[e] = xt8[e]; v1[e] = xt8[4 + e]; }
        *(f32x4*)&ldsA[SWZC(2 * tid) * 4]     = v0;    // xt stage (swz)
        *(f32x4*)&ldsA[SWZC(2 * tid + 1) * 4] = v1;
        if ((tid >> 1) == w) {
          const int b = (tid & 1) * 8;
#pragma unroll
          for (int e = 0; e < 8; ++e) xchunk[b + e] = x8[e];
        }
      }
      __syncthreads();
      {
        // SR partial: col w*16+gl, rows gg*64..+63  (A col-slice streamed)
        float pr = 0.f;
        const float* acp = A + (size_t)(gg * 64) * NDIM + w * 16 + gl;
#pragma unroll 8
        for (int ii = 0; ii < 64; ++ii)
          pr += ntf(acp + (size_t)ii * NDIM) * ldsB[gg * 64 + ii];
        sredA[gg][gl] = pr;
        // G * xt
        float u0 = 0.f, u1 = 0.f, u2 = 0.f, u3 = 0.f;
#pragma unroll
        for (int c4 = 0; c4 < 8; ++c4) {
          const f32x4 kv = *(f32x4*)&ldsA[SWZC(kt * 8 + c4) * 4];
#pragma unroll
          for (int e = 0; e < 4; ++e) {
            const float pv = kv[e];
            const int cc = c4 * 4 + e;
            u0 += Greg[0][cc] * pv; u1 += Greg[1][cc] * pv;
            u2 += Greg[2][cc] * pv; u3 += Greg[3][cc] * pv;
          }
        }
        pmat[q * 4 + 0][kt] = u0; pmat[q * 4 + 1][kt] = u1;
        pmat[q * 4 + 2][kt] = u2; pmat[q * 4 + 3][kt] = u3;
      }
      __syncthreads();
      if (tid < 16) {
        float SR = 0.f;
#pragma unroll
        for (int g32 = 0; g32 < 32; ++g32) SR += sredA[g32][tid];
        float gx = 0.f;
#pragma unroll
        for (int c = 0; c < 32; ++c) {
          const f32x4 vv = *(f32x4*)&pmat[tid][c * 4];
          gx += vv[0] + vv[1] + vv[2] + vv[3];
        }
        const int jl = w * 16 + tid;
        const float xtv = ldsA[SWZC(jl >> 2) * 4 + (jl & 3)];
        const float right = sig * xchunk[tid] - cs_lds[tid] + SR;
        const float Kxt = rho * gx + sig * xtv;
        float* nbw = ((gen + 1) & 1) ? nb1 : nb0;
        staf(nbw + jl, right - Kxt);
      }
      publish();
    }
  }

  // ---------------- output: out = (al*xt + (1-al)*x) * d / gb ------------------
  if ((tid >> 1) == w) {
    const int b = (tid & 1) * 8;
#pragma unroll
    for (int e = 0; e < 8; ++e) {
      const int j = w * 16 + b + e;
      const float xf = al * xt8[e] + (1.f - al) * x8[e];
      out[j] = xf * dvec[j] / gb;
    }
  }
}

extern "C" void kernel_launch(void* const* d_in, const int* in_sizes, int n_in,
                              void* d_out, int out_size, void* d_ws, size_t ws_size,
                              hipStream_t stream) {
  const float* A   = (const float*)d_in[0];
  const float* c   = (const float*)d_in[1];
  const float* lb  = (const float*)d_in[2];
  const float* ub  = (const float*)d_in[3];
  const float* dv  = (const float*)d_in[4];
  const float* ev  = (const float*)d_in[5];
  const float* gc  = (const float*)d_in[6];
  const float* gb  = (const float*)d_in[7];
  const float* rho = (const float*)d_in[8];
  const float* sg  = (const float*)d_in[9];
  const float* al  = (const float*)d_in[10];
  float* out = (float*)d_out;
  unsigned char* ws = (unsigned char*)d_ws;

  // zero kill + flag slots (data buffers start at 49152; all data reads gated)
  (void)hipMemsetAsync(d_ws, 0, 32768, stream);

  admm_lp_kernel<<<dim3(NWG), dim3(NT), 0, stream>>>(
      A, c, lb, ub, dv, ev, gc, gb, rho, sg, al, out, ws);
}